// Round 7
// baseline (2250.974 us; speedup 1.0000x reference)
//
#include <hip/hip_runtime.h>
#include <hip/hip_bf16.h>
#include <hip/hip_fp16.h>

typedef short bf16x8 __attribute__((ext_vector_type(8)));
typedef float f32x4 __attribute__((ext_vector_type(4)));
typedef _Float16 half2v __attribute__((ext_vector_type(2)));
typedef unsigned short u16x4 __attribute__((ext_vector_type(4)));
typedef unsigned int u32x4v __attribute__((ext_vector_type(4)));
typedef unsigned int uint32;

#define MFMA_B16(a,b,c) __builtin_amdgcn_mfma_f32_16x16x32_bf16(a,b,c,0,0,0)

// ---------------- geometry ----------------
#define NS   1024
#define TLEN 128
#define DD   343
#define HH   150
#define GG   600
#define KX   352    // padded DD
#define KXP  44
#define KHP  20
#define NP   640    // padded gate dim

// ---------------- ws layout (bytes) ----------------
#define OFF_WXP  0u          // bf16 [2][44][640][8]
#define OFF_WHP  901120u     // bf16 [2][20][640][8]
#define OFF_B1   1310720u    // f32  [2][640]
#define OFF_W2   1315840u    // f16  [2][600][152]
#define OFF_W2I  1680640u    // f32  [2][300][608]
#define OFF_SE   3139840u    // f32  [1024][300]
#define OFF_XG2  4368640u    // f32  [2][1024][600]
#define OFF_H2O  9283840u    // f32  [1024][300]
#define OFF_XBF  10512640u   // bf16 [1024][128][352] = 92274688
#define NEED_BF  102787328ull

// prep section boundaries
#define PE0 450560
#define PE1 655360
#define PE2 656640
#define PE3 839040
#define PE4 1203840

__device__ __forceinline__ float rcp_fast(float x) { return __builtin_amdgcn_rcpf(x); }
__device__ __forceinline__ float sigm(float x) { return rcp_fast(1.f + __expf(-x)); }
__device__ __forceinline__ float tanh_fast(float x) { return 1.f - 2.f * rcp_fast(__expf(2.f * x) + 1.f); }

typedef __attribute__((address_space(1))) const void GASV;
typedef __attribute__((address_space(3))) void LASV;
__device__ __forceinline__ void gload_lds16(const void* g, void* l) {
  __builtin_amdgcn_global_load_lds((GASV*)g, (LASV*)l, 16, 0, 0);
}

// LDS-only barrier: does NOT drain vmcnt, so global_load_lds prefetch stays in flight.
__device__ __forceinline__ void bar_lds() {
  asm volatile("s_waitcnt lgkmcnt(0)" ::: "memory");
  __builtin_amdgcn_s_barrier();
  asm volatile("" ::: "memory");
}
__device__ __forceinline__ void bar_full() {
  asm volatile("s_waitcnt vmcnt(0) lgkmcnt(0)" ::: "memory");
  __builtin_amdgcn_s_barrier();
  asm volatile("" ::: "memory");
}

__device__ __forceinline__ unsigned short f2bu(float v) {
  __hip_bfloat16 b = __float2bfloat16(v);
  return __builtin_bit_cast(unsigned short, b);
}

// ---------------- prep: pack weights ----------------
__global__ __launch_bounds__(256) void prep_kernel(
    const float* __restrict__ wif1, const float* __restrict__ whf1,
    const float* __restrict__ bif1, const float* __restrict__ bhf1,
    const float* __restrict__ wib1, const float* __restrict__ whb1,
    const float* __restrict__ bib1, const float* __restrict__ bhb1,
    const float* __restrict__ wif2, const float* __restrict__ wib2,
    const float* __restrict__ whf2, const float* __restrict__ whb2,
    __hip_bfloat16* __restrict__ WXp, __hip_bfloat16* __restrict__ WHp,
    float* __restrict__ B1, _Float16* __restrict__ W2, float* __restrict__ W2I)
{
  int i = blockIdx.x * 256 + threadIdx.x;
  if (i < PE0) {
    int d = i / 225280; int r = i - d * 225280;
    int p = r / 5120;   int r2 = r - p * 5120;
    int n = r2 >> 3;    int j = r2 & 7;
    int k = p * 8 + j;
    const float* w = d ? wib1 : wif1;
    float v = (n < GG && k < DD) ? w[n * DD + k] : 0.f;
    WXp[i] = __float2bfloat16(v);
  } else if (i < PE1) {
    int ii = i - PE0;
    int d = ii / 102400; int r = ii - d * 102400;
    int p = r / 5120;    int r2 = r - p * 5120;
    int n = r2 >> 3;     int j = r2 & 7;
    int k = p * 8 + j;
    const float* w = d ? whb1 : whf1;
    float v = (n < GG && k < HH) ? w[n * HH + k] : 0.f;
    WHp[ii] = __float2bfloat16(v);
  } else if (i < PE2) {
    int ii = i - PE1;
    int d = ii / NP; int n = ii - d * NP;
    float v = 0.f;
    if (n < GG) v = d ? (bib1[n] + bhb1[n]) : (bif1[n] + bhf1[n]);
    B1[ii] = v;
  } else if (i < PE3) {
    int ii = i - PE2;
    int d = ii / 91200; int r = ii - d * 91200;
    int n = r / 152;    int k = r - n * 152;
    const float* w = d ? whb2 : whf2;
    float v = (k < HH) ? w[n * HH + k] : 0.f;
    W2[ii] = (_Float16)v;
  } else if (i < PE4) {
    int ii = i - PE3;
    int d = ii / 182400; int r = ii - d * 182400;
    int k = r / 608;     int n = r - k * 608;
    const float* w = d ? wib2 : wif2;
    float v = (n < GG) ? w[n * 300 + k] : 0.f;
    W2I[ii] = v;
  }
}

// ---------------- x -> bf16 padded [S][T][352] ----------------
__global__ __launch_bounds__(256) void xcvt_kernel(
    const float* __restrict__ x, __hip_bfloat16* __restrict__ XBF)
{
  const int total4 = NS * TLEN * (KX / 4);   // 11,534,336
  for (int idx = blockIdx.x * 256 + threadIdx.x; idx < total4; idx += gridDim.x * 256) {
    int row = idx / 88;
    int c4 = (idx - row * 88) * 4;
    const float* src = x + (size_t)row * DD + c4;
    float v0 = 0.f, v1 = 0.f, v2 = 0.f, v3 = 0.f;
    if (c4 + 3 < DD) {
      v0 = __builtin_nontemporal_load(src);
      v1 = __builtin_nontemporal_load(src + 1);
      v2 = __builtin_nontemporal_load(src + 2);
      v3 = __builtin_nontemporal_load(src + 3);
    } else {
      if (c4 < DD)     v0 = src[0];
      if (c4 + 1 < DD) v1 = src[1];
      if (c4 + 2 < DD) v2 = src[2];
    }
    u16x4 o;
    o.x = f2bu(v0); o.y = f2bu(v1); o.z = f2bu(v2); o.w = f2bu(v3);
    u16x4* dst = (u16x4*)((unsigned short*)XBF + (size_t)row * KX + c4);
    __builtin_nontemporal_store(o, dst);
  }
}

// ---------------- layer-1 ----------------
#define XS_SZ   45056u                     // bf16 [4][16][352]
#define HS_OFF  (2u * XS_SZ)               // bf16 [16][160] = 5120
#define GS_OFF  (HS_OFF + 5120u)           // f32  [8][604]  = 19328
#define CF_OFF  (GS_OFF + 19328u)          // f32  [8][152]  = 4864
#define MX_OFF  (CF_OFF + 4864u)           // f32  [8][152]  = 4864
#define L1_SMEM (MX_OFF + 4864u)           // 124288

template<bool BF>
__device__ __forceinline__ void stage_x(char* xsd, const float* __restrict__ x,
                                        const __hip_bfloat16* __restrict__ XBF,
                                        int t0, int dir, int s0, int tid, int lane, int wv)
{
  if constexpr (BF) {
    #pragma unroll
    for (int i = 0; i < 6; ++i) {
      int id = i * 8 + wv;
      if (id < 44) {
        int chunk = id * 64 + lane;
        int row16 = chunk / 44;
        int col16 = chunk - row16 * 44;
        int p = row16 >> 4, rr = row16 & 15;
        int t = t0 + 2 * p + (rr >> 3);
        int s = s0 + (rr & 7);
        int tt = dir ? (127 - t) : t;
        const __hip_bfloat16* gp = XBF + ((size_t)s * TLEN + tt) * KX + col16 * 8;
        gload_lds16((const void*)gp, (void*)(xsd + id * 1024));
      }
    }
  } else {
    for (int e = tid; e < 4 * 16 * KX; e += 512) {
      int row16 = e / KX;
      int col = e - row16 * KX;
      int p = row16 >> 4, rr = row16 & 15;
      int t = t0 + 2 * p + (rr >> 3);
      int s = s0 + (rr & 7);
      int tt = dir ? (127 - t) : t;
      float v = (col < DD) ? x[((size_t)s * TLEN + tt) * DD + col] : 0.f;
      ((__hip_bfloat16*)xsd)[e] = __float2bfloat16(v);
    }
  }
}

__device__ __forceinline__ void cell_pass(float* gs, float* cf, float* mx,
                                          __hip_bfloat16* hs, int tid, bool odd)
{
  for (int e = tid; e < 8 * HH; e += 512) {
    int s = e / HH, j = e - s * HH;
    float iv = sigm(gs[s * 604 + j]);
    float fv = sigm(gs[s * 604 + 150 + j]);
    float gv = tanh_fast(gs[s * 604 + 300 + j]);
    float ov = sigm(gs[s * 604 + 450 + j]);
    float c = fv * cf[s * 152 + j] + iv * gv;
    cf[s * 152 + j] = c;
    float h = ov * tanh_fast(c);
    mx[s * 152 + j] = fmaxf(mx[s * 152 + j], h);
    if (odd) {
      hs[s * 160 + j] = __float2bfloat16(h);
      hs[(8 + s) * 160 + j] = __float2bfloat16(0.f);
    } else {
      hs[(8 + s) * 160 + j] = __float2bfloat16(h);
    }
  }
}

template<bool BF>
__global__ __launch_bounds__(512) __attribute__((amdgpu_waves_per_eu(1, 2)))
void lstm1_kernel(
    const float* __restrict__ x, const __hip_bfloat16* __restrict__ XBF,
    const __hip_bfloat16* __restrict__ WXp, const __hip_bfloat16* __restrict__ WHp,
    const float* __restrict__ B1, float* __restrict__ SE)
{
  extern __shared__ char smem[];
  char* xs0 = smem;
  char* xs1 = smem + XS_SZ;
  __hip_bfloat16* hs = (__hip_bfloat16*)(smem + HS_OFF);
  float* gs = (float*)(smem + GS_OFF);
  float* cf = (float*)(smem + CF_OFF);
  float* mx = (float*)(smem + MX_OFF);

  const int tid = threadIdx.x;
  const int lane = tid & 63;
  const int wv = tid >> 6;
  const int dir = blockIdx.x & 1;
  const int s0 = (blockIdx.x >> 1) * 8;
  const int arow = lane & 15;
  const int kgrp = lane >> 4;
  const int nb = wv * 80;

  for (int e = tid; e < 16 * 160; e += 512) hs[e] = __float2bfloat16(0.f);
  for (int e = tid; e < 8 * 152; e += 512) { cf[e] = 0.f; mx[e] = -3e38f; }

  float bias[5];
  #pragma unroll
  for (int nt = 0; nt < 5; ++nt) {
    int n = nb + nt * 16 + arow;
    bias[nt] = (n < GG) ? B1[dir * NP + n] : 0.f;
    asm volatile("" : "+v"(bias[nt]));
  }

  const __hip_bfloat16* WXd = WXp + (size_t)dir * KXP * NP * 8;
  const __hip_bfloat16* WHd = WHp + (size_t)dir * KHP * NP * 8;

  bf16x8 whr[5][5];
  #pragma unroll
  for (int kh = 0; kh < 5; ++kh)
    #pragma unroll
    for (int nt = 0; nt < 5; ++nt)
      whr[kh][nt] = *reinterpret_cast<const bf16x8*>(
          WHd + ((size_t)(kh * 4 + kgrp) * NP + nb + nt * 16 + arow) * 8);
  #pragma unroll
  for (int kh = 0; kh < 5; ++kh)
    #pragma unroll
    for (int nt = 0; nt < 5; ++nt)
      asm volatile("" : "+v"(whr[kh][nt]));

  stage_x<BF>(xs0, x, XBF, 0, dir, s0, tid, lane, wv);
  bar_full();

  for (int g = 0; g < 16; ++g) {
    char* xsc = (g & 1) ? xs1 : xs0;
    char* xsn = (g & 1) ? xs0 : xs1;
    const __hip_bfloat16* xsb = (const __hip_bfloat16*)xsc;

    f32x4 acc[4][5];
    #pragma unroll
    for (int p = 0; p < 4; ++p)
      #pragma unroll
      for (int nt = 0; nt < 5; ++nt) acc[p][nt] = (f32x4){0.f, 0.f, 0.f, 0.f};

    // ---- phase A: x-projection, 8 steps folded into 4 row-paired tiles ----
    for (int kk = 0; kk < 11; ++kk) {
      bf16x8 a[4], b[5];
      #pragma unroll
      for (int p = 0; p < 4; ++p)
        a[p] = *reinterpret_cast<const bf16x8*>(xsb + (p * 16 + arow) * KX + kk * 32 + kgrp * 8);
      #pragma unroll
      for (int nt = 0; nt < 5; ++nt)
        b[nt] = *reinterpret_cast<const bf16x8*>(
            WXd + ((size_t)(kk * 4 + kgrp) * NP + nb + nt * 16 + arow) * 8);
      #pragma unroll
      for (int p = 0; p < 4; ++p)
        #pragma unroll
        for (int nt = 0; nt < 5; ++nt)
          acc[p][nt] = MFMA_B16(a[p], b[nt], acc[p][nt]);
    }

    // prefetch next g's x while phase B runs (lands by next bar_full)
    if (g < 15)
      stage_x<BF>(xsn, x, XBF, (g + 1) * 8, dir, s0, tid, lane, wv);

    // ---- phase B: 4 pairs = 8 recurrent steps ----
    #pragma unroll
    for (int p = 0; p < 4; ++p) {
      #pragma unroll
      for (int kh = 0; kh < 5; ++kh) {
        bf16x8 ah = *reinterpret_cast<const bf16x8*>(hs + arow * 160 + kh * 32 + kgrp * 8);
        #pragma unroll
        for (int nt = 0; nt < 5; ++nt)
          acc[p][nt] = MFMA_B16(ah, whr[kh][nt], acc[p][nt]);
      }
      if (kgrp < 2) {
        #pragma unroll
        for (int nt = 0; nt < 5; ++nt) {
          int n = nb + nt * 16 + arow;
          if (n < GG) {
            #pragma unroll
            for (int r = 0; r < 4; ++r)
              gs[(kgrp * 4 + r) * 604 + n] = acc[p][nt][r] + bias[nt];
          }
        }
      }
      bar_lds();
      cell_pass(gs, cf, mx, hs, tid, false);   // h_{2p} -> hs rows 8-15
      bar_lds();
      #pragma unroll
      for (int kh = 0; kh < 5; ++kh) {
        bf16x8 ah = *reinterpret_cast<const bf16x8*>(hs + arow * 160 + kh * 32 + kgrp * 8);
        #pragma unroll
        for (int nt = 0; nt < 5; ++nt)
          acc[p][nt] = MFMA_B16(ah, whr[kh][nt], acc[p][nt]);
      }
      if (kgrp >= 2) {
        #pragma unroll
        for (int nt = 0; nt < 5; ++nt) {
          int n = nb + nt * 16 + arow;
          if (n < GG) {
            #pragma unroll
            for (int r = 0; r < 4; ++r)
              gs[((kgrp - 2) * 4 + r) * 604 + n] = acc[p][nt][r] + bias[nt];
          }
        }
      }
      bar_lds();
      cell_pass(gs, cf, mx, hs, tid, true);    // h_{2p+1} -> hs rows 0-7, zero rows 8-15
      if (p == 3) bar_full(); else bar_lds();
    }
  }

  for (int e = tid; e < 8 * HH; e += 512) {
    int s = e / HH, j = e - s * HH;
    SE[(size_t)(s0 + s) * 300 + dir * HH + j] = mx[s * 152 + j];
  }
}

// ---------------- layer-2 input projection ----------------
__global__ __launch_bounds__(256, 1) void xg2_kernel(
    const float* __restrict__ SE, const float* __restrict__ W2I,
    const float* __restrict__ bif2, const float* __restrict__ bhf2,
    const float* __restrict__ bib2, const float* __restrict__ bhb2,
    float* __restrict__ XG2)
{
  __shared__ float se[32 * 304];
  const int d = blockIdx.x >> 5, st = blockIdx.x & 31, sb = st * 32;
  const int tid = threadIdx.x;
  for (int e = tid; e < 32 * 300; e += 256) {
    int si = e / 300, k = e - si * 300;
    se[si * 304 + k] = SE[(size_t)(sb + si) * 300 + k];
  }
  __syncthreads();
  for (int pass = 0; pass < 3; ++pass) {
    int n = pass * 256 + tid;
    if (n < GG) {
      float bias = d ? (bib2[n] + bhb2[n]) : (bif2[n] + bhf2[n]);
      float acc[32];
      #pragma unroll
      for (int si = 0; si < 32; ++si) acc[si] = bias;
      const float* wcol = W2I + (size_t)d * 300 * 608 + n;
      for (int k = 0; k < 300; ++k) {
        float wvv = wcol[(size_t)k * 608];
        #pragma unroll
        for (int si = 0; si < 32; ++si) acc[si] += wvv * se[si * 304 + k];
      }
      #pragma unroll
      for (int si = 0; si < 32; ++si)
        XG2[((size_t)d * NS + sb + si) * GG + n] = acc[si];
    }
  }
}

// ---------------- layer-2 recurrence: weights stashed in PHYSICAL AGPRs ----------------
// The allocator spilled 76 weight dwords to scratch in every VGPR-based variant
// (rounds 4-6: VGPR_Count=48, ~2000cy/step scratch reload). AGPRs a0..a75 are
// outside its budget heuristic entirely: written once via v_accvgpr_write, read
// per use via v_accvgpr_read. Volatile asm keeps program order; named clobbers
// force .agpr_count >= 76 so the HW allocates them.
__global__ __launch_bounds__(640) void lstm2_kernel(
    const _Float16* __restrict__ W2, const float* __restrict__ XG2,
    float* __restrict__ H2O)
{
  const int dir = blockIdx.x;
  const int t = threadIdx.x;
  const int tr = (t < GG) ? t : (GG - 1);   // clamped row: no divergence below
  __shared__ float gls[640];
  __shared__ __align__(16) uint32 hp[80];

  {
    const u32x4v* wr4 = (const u32x4v*)(W2 + ((size_t)dir * GG + tr) * 152);
#define STASH(Q,A0,A1,A2,A3) { u32x4v w = wr4[Q]; \
    asm volatile("v_accvgpr_write_b32 a" #A0 ", %0\n\t" \
                 "v_accvgpr_write_b32 a" #A1 ", %1\n\t" \
                 "v_accvgpr_write_b32 a" #A2 ", %2\n\t" \
                 "v_accvgpr_write_b32 a" #A3 ", %3" \
                 :: "v"(w.x), "v"(w.y), "v"(w.z), "v"(w.w) \
                 : "a" #A0, "a" #A1, "a" #A2, "a" #A3); }
    STASH(0,0,1,2,3)     STASH(1,4,5,6,7)     STASH(2,8,9,10,11)
    STASH(3,12,13,14,15) STASH(4,16,17,18,19) STASH(5,20,21,22,23)
    STASH(6,24,25,26,27) STASH(7,28,29,30,31) STASH(8,32,33,34,35)
    STASH(9,36,37,38,39) STASH(10,40,41,42,43) STASH(11,44,45,46,47)
    STASH(12,48,49,50,51) STASH(13,52,53,54,55) STASH(14,56,57,58,59)
    STASH(15,60,61,62,63) STASH(16,64,65,66,67) STASH(17,68,69,70,71)
    STASH(18,72,73,74,75)
#undef STASH
  }

  if (t < 80) hp[t] = 0u;
  __syncthreads();

  float creg = 0.f;
  const float* xg = XG2 + (size_t)dir * NS * GG;
  const bool isg = (t >= 300) && (t < 450);
  float xnext = xg[(size_t)(dir ? 1023 : 0) * GG + tr];

  for (int step = 0; step < 1024; ++step) {
    const int ss = dir ? (1023 - step) : step;
    float xn = 0.f;
    if (step < 1023) {
      int ss2 = dir ? (1022 - step) : (step + 1);
      xn = xg[(size_t)ss2 * GG + tr];
    }
    const u32x4v* hp4 = reinterpret_cast<const u32x4v*>(hp);
    float a0 = xnext, a1 = 0.f, a2 = 0.f, a3 = 0.f;
#define RD(A, accv, hv) { uint32 wtmp; \
    asm volatile("v_accvgpr_read_b32 %1, a" #A "\n\t" \
                 "v_dot2_f32_f16 %0, %2, %1, %0" \
                 : "+v"(accv), "=&v"(wtmp) : "v"(hv)); }
#define DOTQ(Q,A0,A1,A2,A3) { u32x4v hv = hp4[Q]; \
    RD(A0, a0, hv.x) RD(A1, a1, hv.y) RD(A2, a2, hv.z) RD(A3, a3, hv.w) }
    DOTQ(0,0,1,2,3)     DOTQ(1,4,5,6,7)     DOTQ(2,8,9,10,11)
    DOTQ(3,12,13,14,15) DOTQ(4,16,17,18,19) DOTQ(5,20,21,22,23)
    DOTQ(6,24,25,26,27) DOTQ(7,28,29,30,31) DOTQ(8,32,33,34,35)
    DOTQ(9,36,37,38,39) DOTQ(10,40,41,42,43) DOTQ(11,44,45,46,47)
    DOTQ(12,48,49,50,51) DOTQ(13,52,53,54,55) DOTQ(14,56,57,58,59)
    DOTQ(15,60,61,62,63) DOTQ(16,64,65,66,67) DOTQ(17,68,69,70,71)
    DOTQ(18,72,73,74,75)
#undef DOTQ
#undef RD
    float acc = (a0 + a1) + (a2 + a3);
    gls[t] = isg ? tanh_fast(acc) : sigm(acc);
    bar_lds();
    if (t < HH) {
      float iv = gls[t], fv = gls[150 + t], gv = gls[300 + t], ov = gls[450 + t];
      creg = fv * creg + iv * gv;
      float nh = ov * tanh_fast(creg);
      H2O[(size_t)ss * 300 + dir * HH + t] = nh;
      ((ushort*)hp)[t] = __half_as_ushort(__float2half(nh));
    }
    bar_lds();
    xnext = xn;
  }
}

// ---------------- head ----------------
__global__ __launch_bounds__(256, 1) void head_kernel(
    const float* __restrict__ H2O, const float* __restrict__ w_out,
    const float* __restrict__ b_out, float* __restrict__ out)
{
  int s = blockIdx.x * 256 + threadIdx.x;
  if (s >= NS) return;
  float acc[7];
  #pragma unroll
  for (int c = 0; c < 7; ++c) acc[c] = b_out[c];
  const float* hrow = H2O + (size_t)s * 300;
  for (int k = 0; k < 300; ++k) {
    float hv = hrow[k];
    #pragma unroll
    for (int c = 0; c < 7; ++c) acc[c] += hv * w_out[c * 300 + k];
  }
  float m = acc[0];
  #pragma unroll
  for (int c = 1; c < 7; ++c) m = fmaxf(m, acc[c]);
  float sum = 0.f;
  #pragma unroll
  for (int c = 0; c < 7; ++c) sum += __expf(acc[c] - m);
  float lse = m + __logf(sum);
  #pragma unroll
  for (int c = 0; c < 7; ++c) out[s * 7 + c] = acc[c] - lse;
}

extern "C" void kernel_launch(void* const* d_in, const int* in_sizes, int n_in,
                              void* d_out, int out_size, void* d_ws, size_t ws_size,
                              hipStream_t stream) {
  const float* x      = (const float*)d_in[0];
  const float* wif1   = (const float*)d_in[1];
  const float* whf1   = (const float*)d_in[2];
  const float* bif1   = (const float*)d_in[3];
  const float* bhf1   = (const float*)d_in[4];
  const float* wib1   = (const float*)d_in[5];
  const float* whb1   = (const float*)d_in[6];
  const float* bib1   = (const float*)d_in[7];
  const float* bhb1   = (const float*)d_in[8];
  const float* wif2   = (const float*)d_in[9];
  const float* whf2   = (const float*)d_in[10];
  const float* bif2   = (const float*)d_in[11];
  const float* bhf2   = (const float*)d_in[12];
  const float* wib2   = (const float*)d_in[13];
  const float* whb2   = (const float*)d_in[14];
  const float* bib2   = (const float*)d_in[15];
  const float* bhb2   = (const float*)d_in[16];
  const float* w_out  = (const float*)d_in[17];
  const float* b_out  = (const float*)d_in[18];

  char* ws = (char*)d_ws;
  __hip_bfloat16* WXp = (__hip_bfloat16*)(ws + OFF_WXP);
  __hip_bfloat16* WHp = (__hip_bfloat16*)(ws + OFF_WHP);
  float*    B1  = (float*)(ws + OFF_B1);
  _Float16* W2  = (_Float16*)(ws + OFF_W2);
  float*    W2I = (float*)(ws + OFF_W2I);
  float*    SE  = (float*)(ws + OFF_SE);
  float*    XG2 = (float*)(ws + OFF_XG2);
  float*    H2O = (float*)(ws + OFF_H2O);
  __hip_bfloat16* XBF = (__hip_bfloat16*)(ws + OFF_XBF);

  const bool useBF = (ws_size >= NEED_BF);

  prep_kernel<<<(PE4 + 255) / 256, 256, 0, stream>>>(
      wif1, whf1, bif1, bhf1, wib1, whb1, bib1, bhb1,
      wif2, wib2, whf2, whb2, WXp, WHp, B1, W2, W2I);

  if (useBF)
    xcvt_kernel<<<4096, 256, 0, stream>>>(x, XBF);

  (void)hipFuncSetAttribute((const void*)(lstm1_kernel<true>),
                            hipFuncAttributeMaxDynamicSharedMemorySize, L1_SMEM);
  (void)hipFuncSetAttribute((const void*)(lstm1_kernel<false>),
                            hipFuncAttributeMaxDynamicSharedMemorySize, L1_SMEM);

  if (useBF)
    lstm1_kernel<true><<<256, 512, L1_SMEM, stream>>>(x, XBF, WXp, WHp, B1, SE);
  else
    lstm1_kernel<false><<<256, 512, L1_SMEM, stream>>>(x, XBF, WXp, WHp, B1, SE);

  xg2_kernel<<<64, 256, 0, stream>>>(SE, W2I, bif2, bhf2, bib2, bhb2, XG2);

  lstm2_kernel<<<2, 640, 0, stream>>>(W2, XG2, H2O);

  head_kernel<<<4, 256, 0, stream>>>(H2O, w_out, b_out, (float*)d_out);
}

// Round 8
// 1592.706 us; speedup vs baseline: 1.4133x; 1.4133x over previous
//
#include <hip/hip_runtime.h>
#include <hip/hip_bf16.h>
#include <hip/hip_fp16.h>

typedef short bf16x8 __attribute__((ext_vector_type(8)));
typedef float f32x4 __attribute__((ext_vector_type(4)));
typedef unsigned short u16x4 __attribute__((ext_vector_type(4)));
typedef unsigned int uint32;

#define MFMA_B16(a,b,c) __builtin_amdgcn_mfma_f32_16x16x32_bf16(a,b,c,0,0,0)

// ---------------- geometry ----------------
#define NS   1024
#define TLEN 128
#define DD   343
#define HH   150
#define GG   600
#define KX   352    // padded DD
#define KXP  44
#define KHP  20
#define NP   640    // padded gate dim

// ---------------- ws layout (bytes) ----------------
#define OFF_WXP  0u          // bf16 [2][44][640][8]   901120
#define OFF_WHP  901120u     // bf16 [2][20][640][8]   409600
#define OFF_B1   1310720u    // f32  [2][640]          5120
#define OFF_W2B  1315840u    // bf16 [2][640][160]     409600
#define OFF_W2I  1725440u    // f32  [2][300][608]     1459200
#define OFF_SE   3184640u    // f32  [1024][300]       1228800
#define OFF_XG2  4413440u    // f32  [2][1024][600]    4915200
#define OFF_H2O  9328640u    // f32  [1024][300]       1228800
#define OFF_XBF  10557440u   // bf16 [1024][128][352]  92274688
#define NEED_BF  102832128ull

// prep section boundaries (element counts)
#define PE0 450560            // WXp
#define PE1 655360            // + WHp 204800
#define PE2 656640            // + B1 1280
#define PE3 861440            // + W2B 204800
#define PE4 1226240           // + W2I 364800

__device__ __forceinline__ float rcp_fast(float x) { return __builtin_amdgcn_rcpf(x); }
__device__ __forceinline__ float sigm(float x) { return rcp_fast(1.f + __expf(-x)); }
__device__ __forceinline__ float tanh_fast(float x) { return 1.f - 2.f * rcp_fast(__expf(2.f * x) + 1.f); }

typedef __attribute__((address_space(1))) const void GASV;
typedef __attribute__((address_space(3))) void LASV;
__device__ __forceinline__ void gload_lds16(const void* g, void* l) {
  __builtin_amdgcn_global_load_lds((GASV*)g, (LASV*)l, 16, 0, 0);
}

// LDS-only barrier: does NOT drain vmcnt, so global_load_lds prefetch stays in flight.
__device__ __forceinline__ void bar_lds() {
  asm volatile("s_waitcnt lgkmcnt(0)" ::: "memory");
  __builtin_amdgcn_s_barrier();
  asm volatile("" ::: "memory");
}
__device__ __forceinline__ void bar_full() {
  asm volatile("s_waitcnt vmcnt(0) lgkmcnt(0)" ::: "memory");
  __builtin_amdgcn_s_barrier();
  asm volatile("" ::: "memory");
}

__device__ __forceinline__ unsigned short f2bu(float v) {
  __hip_bfloat16 b = __float2bfloat16(v);
  return __builtin_bit_cast(unsigned short, b);
}

// ---------------- prep: pack weights ----------------
__global__ __launch_bounds__(256) void prep_kernel(
    const float* __restrict__ wif1, const float* __restrict__ whf1,
    const float* __restrict__ bif1, const float* __restrict__ bhf1,
    const float* __restrict__ wib1, const float* __restrict__ whb1,
    const float* __restrict__ bib1, const float* __restrict__ bhb1,
    const float* __restrict__ wif2, const float* __restrict__ wib2,
    const float* __restrict__ whf2, const float* __restrict__ whb2,
    __hip_bfloat16* __restrict__ WXp, __hip_bfloat16* __restrict__ WHp,
    float* __restrict__ B1, __hip_bfloat16* __restrict__ W2B, float* __restrict__ W2I)
{
  int i = blockIdx.x * 256 + threadIdx.x;
  if (i < PE0) {
    int d = i / 225280; int r = i - d * 225280;
    int p = r / 5120;   int r2 = r - p * 5120;
    int n = r2 >> 3;    int j = r2 & 7;
    int k = p * 8 + j;
    const float* w = d ? wib1 : wif1;
    float v = (n < GG && k < DD) ? w[n * DD + k] : 0.f;
    WXp[i] = __float2bfloat16(v);
  } else if (i < PE1) {
    int ii = i - PE0;
    int d = ii / 102400; int r = ii - d * 102400;
    int p = r / 5120;    int r2 = r - p * 5120;
    int n = r2 >> 3;     int j = r2 & 7;
    int k = p * 8 + j;
    const float* w = d ? whb1 : whf1;
    float v = (n < GG && k < HH) ? w[n * HH + k] : 0.f;
    WHp[ii] = __float2bfloat16(v);
  } else if (i < PE2) {
    int ii = i - PE1;
    int d = ii / NP; int n = ii - d * NP;
    float v = 0.f;
    if (n < GG) v = d ? (bib1[n] + bhb1[n]) : (bif1[n] + bhf1[n]);
    B1[ii] = v;
  } else if (i < PE3) {
    // W2B[d][n][k] (n<640 pad, k<160 pad) = w_hh2[n][k] as bf16
    int ii = i - PE2;
    int d = ii / 102400; int r = ii - d * 102400;
    int n = r / 160;     int k = r - n * 160;
    const float* w = d ? whb2 : whf2;
    float v = (n < GG && k < HH) ? w[n * HH + k] : 0.f;
    W2B[ii] = __float2bfloat16(v);
  } else if (i < PE4) {
    int ii = i - PE3;
    int d = ii / 182400; int r = ii - d * 182400;
    int k = r / 608;     int n = r - k * 608;
    const float* w = d ? wib2 : wif2;
    float v = (n < GG) ? w[n * 300 + k] : 0.f;
    W2I[ii] = v;
  }
}

// ---------------- x -> bf16 padded [S][T][352] ----------------
__global__ __launch_bounds__(256) void xcvt_kernel(
    const float* __restrict__ x, __hip_bfloat16* __restrict__ XBF)
{
  const int total4 = NS * TLEN * (KX / 4);   // 11,534,336
  for (int idx = blockIdx.x * 256 + threadIdx.x; idx < total4; idx += gridDim.x * 256) {
    int row = idx / 88;
    int c4 = (idx - row * 88) * 4;
    const float* src = x + (size_t)row * DD + c4;
    float v0 = 0.f, v1 = 0.f, v2 = 0.f, v3 = 0.f;
    if (c4 + 3 < DD) {
      v0 = __builtin_nontemporal_load(src);
      v1 = __builtin_nontemporal_load(src + 1);
      v2 = __builtin_nontemporal_load(src + 2);
      v3 = __builtin_nontemporal_load(src + 3);
    } else {
      if (c4 < DD)     v0 = src[0];
      if (c4 + 1 < DD) v1 = src[1];
      if (c4 + 2 < DD) v2 = src[2];
    }
    u16x4 o;
    o.x = f2bu(v0); o.y = f2bu(v1); o.z = f2bu(v2); o.w = f2bu(v3);
    u16x4* dst = (u16x4*)((unsigned short*)XBF + (size_t)row * KX + c4);
    __builtin_nontemporal_store(o, dst);
  }
}

// ---------------- layer-1 ----------------
#define XS_SZ   45056u                     // bf16 [4][16][352]
#define HS_OFF  (2u * XS_SZ)               // bf16 [16][160] = 5120
#define GS_OFF  (HS_OFF + 5120u)           // f32  [8][604]  = 19328
#define CF_OFF  (GS_OFF + 19328u)          // f32  [8][152]  = 4864
#define MX_OFF  (CF_OFF + 4864u)           // f32  [8][152]  = 4864
#define L1_SMEM (MX_OFF + 4864u)           // 124288

template<bool BF>
__device__ __forceinline__ void stage_x(char* xsd, const float* __restrict__ x,
                                        const __hip_bfloat16* __restrict__ XBF,
                                        int t0, int dir, int s0, int tid, int lane, int wv)
{
  if constexpr (BF) {
    #pragma unroll
    for (int i = 0; i < 6; ++i) {
      int id = i * 8 + wv;
      if (id < 44) {
        int chunk = id * 64 + lane;
        int row16 = chunk / 44;
        int col16 = chunk - row16 * 44;
        int p = row16 >> 4, rr = row16 & 15;
        int t = t0 + 2 * p + (rr >> 3);
        int s = s0 + (rr & 7);
        int tt = dir ? (127 - t) : t;
        const __hip_bfloat16* gp = XBF + ((size_t)s * TLEN + tt) * KX + col16 * 8;
        gload_lds16((const void*)gp, (void*)(xsd + id * 1024));
      }
    }
  } else {
    for (int e = tid; e < 4 * 16 * KX; e += 512) {
      int row16 = e / KX;
      int col = e - row16 * KX;
      int p = row16 >> 4, rr = row16 & 15;
      int t = t0 + 2 * p + (rr >> 3);
      int s = s0 + (rr & 7);
      int tt = dir ? (127 - t) : t;
      float v = (col < DD) ? x[((size_t)s * TLEN + tt) * DD + col] : 0.f;
      ((__hip_bfloat16*)xsd)[e] = __float2bfloat16(v);
    }
  }
}

__device__ __forceinline__ void cell_pass(float* gs, float* cf, float* mx,
                                          __hip_bfloat16* hs, int tid, bool odd)
{
  for (int e = tid; e < 8 * HH; e += 512) {
    int s = e / HH, j = e - s * HH;
    float iv = sigm(gs[s * 604 + j]);
    float fv = sigm(gs[s * 604 + 150 + j]);
    float gv = tanh_fast(gs[s * 604 + 300 + j]);
    float ov = sigm(gs[s * 604 + 450 + j]);
    float c = fv * cf[s * 152 + j] + iv * gv;
    cf[s * 152 + j] = c;
    float h = ov * tanh_fast(c);
    mx[s * 152 + j] = fmaxf(mx[s * 152 + j], h);
    if (odd) {
      hs[s * 160 + j] = __float2bfloat16(h);
      hs[(8 + s) * 160 + j] = __float2bfloat16(0.f);
    } else {
      hs[(8 + s) * 160 + j] = __float2bfloat16(h);
    }
  }
}

template<bool BF>
__global__ __launch_bounds__(512) __attribute__((amdgpu_waves_per_eu(1, 2)))
void lstm1_kernel(
    const float* __restrict__ x, const __hip_bfloat16* __restrict__ XBF,
    const __hip_bfloat16* __restrict__ WXp, const __hip_bfloat16* __restrict__ WHp,
    const float* __restrict__ B1, float* __restrict__ SE)
{
  extern __shared__ char smem[];
  char* xs0 = smem;
  char* xs1 = smem + XS_SZ;
  __hip_bfloat16* hs = (__hip_bfloat16*)(smem + HS_OFF);
  float* gs = (float*)(smem + GS_OFF);
  float* cf = (float*)(smem + CF_OFF);
  float* mx = (float*)(smem + MX_OFF);

  const int tid = threadIdx.x;
  const int lane = tid & 63;
  const int wv = tid >> 6;
  const int dir = blockIdx.x & 1;
  const int s0 = (blockIdx.x >> 1) * 8;
  const int arow = lane & 15;
  const int kgrp = lane >> 4;
  const int nb = wv * 80;

  for (int e = tid; e < 16 * 160; e += 512) hs[e] = __float2bfloat16(0.f);
  for (int e = tid; e < 8 * 152; e += 512) { cf[e] = 0.f; mx[e] = -3e38f; }

  float bias[5];
  #pragma unroll
  for (int nt = 0; nt < 5; ++nt) {
    int n = nb + nt * 16 + arow;
    bias[nt] = (n < GG) ? B1[dir * NP + n] : 0.f;
    asm volatile("" : "+v"(bias[nt]));
  }

  const __hip_bfloat16* WXd = WXp + (size_t)dir * KXP * NP * 8;
  const __hip_bfloat16* WHd = WHp + (size_t)dir * KHP * NP * 8;

  bf16x8 whr[5][5];
  #pragma unroll
  for (int kh = 0; kh < 5; ++kh)
    #pragma unroll
    for (int nt = 0; nt < 5; ++nt)
      whr[kh][nt] = *reinterpret_cast<const bf16x8*>(
          WHd + ((size_t)(kh * 4 + kgrp) * NP + nb + nt * 16 + arow) * 8);
  #pragma unroll
  for (int kh = 0; kh < 5; ++kh)
    #pragma unroll
    for (int nt = 0; nt < 5; ++nt)
      asm volatile("" : "+v"(whr[kh][nt]));

  stage_x<BF>(xs0, x, XBF, 0, dir, s0, tid, lane, wv);
  bar_full();

  for (int g = 0; g < 16; ++g) {
    char* xsc = (g & 1) ? xs1 : xs0;
    char* xsn = (g & 1) ? xs0 : xs1;
    const __hip_bfloat16* xsb = (const __hip_bfloat16*)xsc;

    f32x4 acc[4][5];
    #pragma unroll
    for (int p = 0; p < 4; ++p)
      #pragma unroll
      for (int nt = 0; nt < 5; ++nt) acc[p][nt] = (f32x4){0.f, 0.f, 0.f, 0.f};

    // ---- phase A: x-projection, 8 steps folded into 4 row-paired tiles ----
    for (int kk = 0; kk < 11; ++kk) {
      bf16x8 a[4], b[5];
      #pragma unroll
      for (int p = 0; p < 4; ++p)
        a[p] = *reinterpret_cast<const bf16x8*>(xsb + (p * 16 + arow) * KX + kk * 32 + kgrp * 8);
      #pragma unroll
      for (int nt = 0; nt < 5; ++nt)
        b[nt] = *reinterpret_cast<const bf16x8*>(
            WXd + ((size_t)(kk * 4 + kgrp) * NP + nb + nt * 16 + arow) * 8);
      #pragma unroll
      for (int p = 0; p < 4; ++p)
        #pragma unroll
        for (int nt = 0; nt < 5; ++nt)
          acc[p][nt] = MFMA_B16(a[p], b[nt], acc[p][nt]);
    }

    // prefetch next g's x while phase B runs (lands by next bar_full)
    if (g < 15)
      stage_x<BF>(xsn, x, XBF, (g + 1) * 8, dir, s0, tid, lane, wv);

    // ---- phase B: 4 pairs = 8 recurrent steps ----
    #pragma unroll
    for (int p = 0; p < 4; ++p) {
      #pragma unroll
      for (int kh = 0; kh < 5; ++kh) {
        bf16x8 ah = *reinterpret_cast<const bf16x8*>(hs + arow * 160 + kh * 32 + kgrp * 8);
        #pragma unroll
        for (int nt = 0; nt < 5; ++nt)
          acc[p][nt] = MFMA_B16(ah, whr[kh][nt], acc[p][nt]);
      }
      if (kgrp < 2) {
        #pragma unroll
        for (int nt = 0; nt < 5; ++nt) {
          int n = nb + nt * 16 + arow;
          if (n < GG) {
            #pragma unroll
            for (int r = 0; r < 4; ++r)
              gs[(kgrp * 4 + r) * 604 + n] = acc[p][nt][r] + bias[nt];
          }
        }
      }
      bar_lds();
      cell_pass(gs, cf, mx, hs, tid, false);   // h_{2p} -> hs rows 8-15
      bar_lds();
      #pragma unroll
      for (int kh = 0; kh < 5; ++kh) {
        bf16x8 ah = *reinterpret_cast<const bf16x8*>(hs + arow * 160 + kh * 32 + kgrp * 8);
        #pragma unroll
        for (int nt = 0; nt < 5; ++nt)
          acc[p][nt] = MFMA_B16(ah, whr[kh][nt], acc[p][nt]);
      }
      if (kgrp >= 2) {
        #pragma unroll
        for (int nt = 0; nt < 5; ++nt) {
          int n = nb + nt * 16 + arow;
          if (n < GG) {
            #pragma unroll
            for (int r = 0; r < 4; ++r)
              gs[((kgrp - 2) * 4 + r) * 604 + n] = acc[p][nt][r] + bias[nt];
          }
        }
      }
      bar_lds();
      cell_pass(gs, cf, mx, hs, tid, true);    // h_{2p+1} -> hs rows 0-7, zero rows 8-15
      if (p == 3) bar_full(); else bar_lds();
    }
  }

  for (int e = tid; e < 8 * HH; e += 512) {
    int s = e / HH, j = e - s * HH;
    SE[(size_t)(s0 + s) * 300 + dir * HH + j] = mx[s * 152 + j];
  }
}

// ---------------- layer-2 input projection ----------------
__global__ __launch_bounds__(256, 1) void xg2_kernel(
    const float* __restrict__ SE, const float* __restrict__ W2I,
    const float* __restrict__ bif2, const float* __restrict__ bhf2,
    const float* __restrict__ bib2, const float* __restrict__ bhb2,
    float* __restrict__ XG2)
{
  __shared__ float se[32 * 304];
  const int d = blockIdx.x >> 5, st = blockIdx.x & 31, sb = st * 32;
  const int tid = threadIdx.x;
  for (int e = tid; e < 32 * 300; e += 256) {
    int si = e / 300, k = e - si * 300;
    se[si * 304 + k] = SE[(size_t)(sb + si) * 300 + k];
  }
  __syncthreads();
  for (int pass = 0; pass < 3; ++pass) {
    int n = pass * 256 + tid;
    if (n < GG) {
      float bias = d ? (bib2[n] + bhb2[n]) : (bif2[n] + bhf2[n]);
      float acc[32];
      #pragma unroll
      for (int si = 0; si < 32; ++si) acc[si] = bias;
      const float* wcol = W2I + (size_t)d * 300 * 608 + n;
      for (int k = 0; k < 300; ++k) {
        float wvv = wcol[(size_t)k * 608];
        #pragma unroll
        for (int si = 0; si < 32; ++si) acc[si] += wvv * se[si * 304 + k];
      }
      #pragma unroll
      for (int si = 0; si < 32; ++si)
        XG2[((size_t)d * NS + sb + si) * GG + n] = acc[si];
    }
  }
}

// ---------------- layer-2 recurrence via MFMA ----------------
// y[600] = W_hh*h computed as D = Hrep(16xK) x Wt(Kx16) per 16-col tile.
// A-frag: h broadcast (addr depends only on lane>>4 -> LDS broadcast read of a
// 320B h buffer; all 16 A-rows identical). 10 waves x 4 ntiles = 640 cols.
// Wave's W-frags: 20 x bf16x8 = 80 VGPRs, loaded once -- MFMA operands, which
// the backend keeps register-resident (unlike rounds 4-7's scalar loads).
// D layout (col=lane&15, row=(lane>>4)*4+r): lane(c,kg) reg0 of acc[kg] is
// y[wv*64+kg*16+c] == y[tid] -- each thread owns its own gate column.
__global__ __launch_bounds__(640) __attribute__((amdgpu_waves_per_eu(1, 3)))
void lstm2_kernel(
    const __hip_bfloat16* __restrict__ W2B, const float* __restrict__ XG2,
    float* __restrict__ H2O)
{
  const int dir = blockIdx.x;
  const int tid = threadIdx.x;
  const int lane = tid & 63;
  const int wv = tid >> 6;        // 0..9
  const int c16 = lane & 15;
  const int kg = lane >> 4;       // 0..3
  __shared__ float gls[NP];
  __shared__ __align__(16) __hip_bfloat16 hbuf[160];

  const __hip_bfloat16* Wd = W2B + (size_t)dir * NP * 160;
  bf16x8 wf[5][4];
  #pragma unroll
  for (int kt = 0; kt < 5; ++kt)
    #pragma unroll
    for (int nt = 0; nt < 4; ++nt)
      wf[kt][nt] = *reinterpret_cast<const bf16x8*>(
          Wd + (size_t)(wv * 64 + nt * 16 + c16) * 160 + kt * 32 + kg * 8);

  if (tid < 160) hbuf[tid] = __float2bfloat16(0.f);
  __syncthreads();

  float creg = 0.f;
  const float* xg = XG2 + (size_t)dir * NS * GG;
  const int gcol = (tid < GG) ? tid : (GG - 1);
  const bool isg = (tid >= 300) && (tid < 450);
  float xnext = xg[(size_t)(dir ? 1023 : 0) * GG + gcol];

  for (int step = 0; step < 1024; ++step) {
    const int ss = dir ? (1023 - step) : step;
    float xn = 0.f;
    if (step < 1023) {
      int ss2 = dir ? (1022 - step) : (step + 1);
      xn = xg[(size_t)ss2 * GG + gcol];
    }
    bf16x8 hf[5];
    #pragma unroll
    for (int kt = 0; kt < 5; ++kt)
      hf[kt] = *reinterpret_cast<const bf16x8*>(hbuf + kt * 32 + kg * 8);
    f32x4 a0 = {0.f,0.f,0.f,0.f}, a1 = {0.f,0.f,0.f,0.f};
    f32x4 a2 = {0.f,0.f,0.f,0.f}, a3 = {0.f,0.f,0.f,0.f};
    #pragma unroll
    for (int kt = 0; kt < 5; ++kt) {
      a0 = MFMA_B16(hf[kt], wf[kt][0], a0);
      a1 = MFMA_B16(hf[kt], wf[kt][1], a1);
      a2 = MFMA_B16(hf[kt], wf[kt][2], a2);
      a3 = MFMA_B16(hf[kt], wf[kt][3], a3);
    }
    float y = (kg == 0) ? a0[0] : (kg == 1) ? a1[0] : (kg == 2) ? a2[0] : a3[0];
    float acc = y + xnext;
    gls[tid] = isg ? tanh_fast(acc) : sigm(acc);
    bar_lds();
    if (tid < HH) {
      float iv = gls[tid], fv = gls[150 + tid], gv = gls[300 + tid], ov = gls[450 + tid];
      creg = fv * creg + iv * gv;
      float nh = ov * tanh_fast(creg);
      H2O[(size_t)ss * 300 + dir * HH + tid] = nh;
      hbuf[tid] = __float2bfloat16(nh);
    }
    bar_lds();
    xnext = xn;
  }
}

// ---------------- head ----------------
__global__ __launch_bounds__(256, 1) void head_kernel(
    const float* __restrict__ H2O, const float* __restrict__ w_out,
    const float* __restrict__ b_out, float* __restrict__ out)
{
  int s = blockIdx.x * 256 + threadIdx.x;
  if (s >= NS) return;
  float acc[7];
  #pragma unroll
  for (int c = 0; c < 7; ++c) acc[c] = b_out[c];
  const float* hrow = H2O + (size_t)s * 300;
  for (int k = 0; k < 300; ++k) {
    float hv = hrow[k];
    #pragma unroll
    for (int c = 0; c < 7; ++c) acc[c] += hv * w_out[c * 300 + k];
  }
  float m = acc[0];
  #pragma unroll
  for (int c = 1; c < 7; ++c) m = fmaxf(m, acc[c]);
  float sum = 0.f;
  #pragma unroll
  for (int c = 0; c < 7; ++c) sum += __expf(acc[c] - m);
  float lse = m + __logf(sum);
  #pragma unroll
  for (int c = 0; c < 7; ++c) out[s * 7 + c] = acc[c] - lse;
}

extern "C" void kernel_launch(void* const* d_in, const int* in_sizes, int n_in,
                              void* d_out, int out_size, void* d_ws, size_t ws_size,
                              hipStream_t stream) {
  const float* x      = (const float*)d_in[0];
  const float* wif1   = (const float*)d_in[1];
  const float* whf1   = (const float*)d_in[2];
  const float* bif1   = (const float*)d_in[3];
  const float* bhf1   = (const float*)d_in[4];
  const float* wib1   = (const float*)d_in[5];
  const float* whb1   = (const float*)d_in[6];
  const float* bib1   = (const float*)d_in[7];
  const float* bhb1   = (const float*)d_in[8];
  const float* wif2   = (const float*)d_in[9];
  const float* whf2   = (const float*)d_in[10];
  const float* bif2   = (const float*)d_in[11];
  const float* bhf2   = (const float*)d_in[12];
  const float* wib2   = (const float*)d_in[13];
  const float* whb2   = (const float*)d_in[14];
  const float* bib2   = (const float*)d_in[15];
  const float* bhb2   = (const float*)d_in[16];
  const float* w_out  = (const float*)d_in[17];
  const float* b_out  = (const float*)d_in[18];

  char* ws = (char*)d_ws;
  __hip_bfloat16* WXp = (__hip_bfloat16*)(ws + OFF_WXP);
  __hip_bfloat16* WHp = (__hip_bfloat16*)(ws + OFF_WHP);
  float*    B1  = (float*)(ws + OFF_B1);
  __hip_bfloat16* W2B = (__hip_bfloat16*)(ws + OFF_W2B);
  float*    W2I = (float*)(ws + OFF_W2I);
  float*    SE  = (float*)(ws + OFF_SE);
  float*    XG2 = (float*)(ws + OFF_XG2);
  float*    H2O = (float*)(ws + OFF_H2O);
  __hip_bfloat16* XBF = (__hip_bfloat16*)(ws + OFF_XBF);

  const bool useBF = (ws_size >= NEED_BF);

  prep_kernel<<<(PE4 + 255) / 256, 256, 0, stream>>>(
      wif1, whf1, bif1, bhf1, wib1, whb1, bib1, bhb1,
      wif2, wib2, whf2, whb2, WXp, WHp, B1, W2B, W2I);

  if (useBF)
    xcvt_kernel<<<4096, 256, 0, stream>>>(x, XBF);

  (void)hipFuncSetAttribute((const void*)(lstm1_kernel<true>),
                            hipFuncAttributeMaxDynamicSharedMemorySize, L1_SMEM);
  (void)hipFuncSetAttribute((const void*)(lstm1_kernel<false>),
                            hipFuncAttributeMaxDynamicSharedMemorySize, L1_SMEM);

  if (useBF)
    lstm1_kernel<true><<<256, 512, L1_SMEM, stream>>>(x, XBF, WXp, WHp, B1, SE);
  else
    lstm1_kernel<false><<<256, 512, L1_SMEM, stream>>>(x, XBF, WXp, WHp, B1, SE);

  xg2_kernel<<<64, 256, 0, stream>>>(SE, W2I, bif2, bhf2, bib2, bhb2, XG2);

  lstm2_kernel<<<2, 640, 0, stream>>>(W2B, XG2, H2O);

  head_kernel<<<4, 256, 0, stream>>>(H2O, w_out, b_out, (float*)d_out);
}